// Round 3
// baseline (84.296 us; speedup 1.0000x reference)
//
#include <hip/hip_runtime.h>
#include <hip/hip_bf16.h>

#ifndef __has_builtin
#define __has_builtin(x) 0
#endif

typedef __attribute__((ext_vector_type(8))) short short8;   // 8 bf16 = 4 VGPRs
typedef __attribute__((ext_vector_type(4))) float floatx4;  // MFMA C/D

__device__ __forceinline__ float fast_exp2(float x) {
#if __has_builtin(__builtin_amdgcn_exp2f)
    return __builtin_amdgcn_exp2f(x);
#else
    return exp2f(x);
#endif
}
__device__ __forceinline__ float fast_rcp(float x) {
#if __has_builtin(__builtin_amdgcn_rcpf)
    return __builtin_amdgcn_rcpf(x);
#else
    return 1.0f / x;
#endif
}
__device__ __forceinline__ unsigned short bf16_of(float v) {
    union { __hip_bfloat16 b; unsigned short s; } cv;
    cv.b = __float2bfloat16(v);
    return cv.s;
}
__device__ __forceinline__ float bf16_back(unsigned short s) {
    union { __hip_bfloat16 b; unsigned short t; } cv;
    cv.t = s;
    return __bfloat162float(cv.b);
}
__device__ __forceinline__ unsigned bcat(unsigned short lo, unsigned short hi) {
    return (unsigned)lo | ((unsigned)hi << 16);   // slot j even = low half
}
__device__ __forceinline__ unsigned pack_bf16(float a, float b) {
    __hip_bfloat162 h = __float22bfloat162_rn(make_float2(a, b));
    union { __hip_bfloat162 h2; unsigned u; } cv;
    cv.h2 = h;
    return cv.u;
}

#define VQ_K 256
#define BLK  256    // R15: back to 4-wave blocks, lb(256,4) -> 128-VGPR headroom
#define T    4      // 64 m per wave; grid 2048 for fast residency ramp.

// R15 discriminating experiment. Facts so far: (R2) the 256 MiB ws poison is
// UNCONDITIONAL (~42 us/iter, timed); (R13/R14) table bandwidth, ILP (T=2->4),
// and table location (L1 vs LDS) all null -> vq_main is either stall-bound on
// the chunk-loop dependency chain / residency ramp, or already ~10-15 us with
// the rest of the 82 us being harness reset overhead (tiny dispatches + gaps).
// This round attacks the stall terms with invariant math:
//   - software-pipelined c-loop (prefetch next chunk's frags into regs)
//   - no exec-mask on A-loads (q>=2 lanes read garbage; B-slots there are 0)
//   - 256-thread blocks, lb(256,4): VGPR cap 128, finer placement
// Math identical to R9/R13: S^T = C2ext*Xext via 16x16x32 bf16 MFMA, 13-slot
// error-compensated split, p=exp2(S) packed in-lane, pi-perm baked into V',
// D col 4 = denominator. If this is flat too -> harness floor -> ROOFLINE.

__global__ __launch_bounds__(BLK, 4) void vq_main(const float* __restrict__ x,
                                                  const float* __restrict__ center,
                                                  float* __restrict__ out) {
    __shared__ uint4 tbl[1024];                 // [0..511]=compact A-frags, [512..1023]=V'-frags

    // ---- per-block table build; 256 threads x 4 entries each ----
    {
        const float L2E = 1.4426950408889634f;
        for (int f = threadIdx.x; f < 1024; f += BLK) {
            if (f < 512) {
                // compact A-frag: entry e=f>>5 (0..15), lane32=f&31 (q in {0,1})
                int lane32 = f & 31;
                int qq = lane32 >> 4;
                int mm = lane32 & 15;
                int k  = (f >> 5) * 16 + mm;
                float4 c = reinterpret_cast<const float4*>(center)[k];
                float s = 2.0f * L2E;
                float c2f[4] = {s * c.x, s * c.y, s * c.z, s * c.w};
                unsigned short ch[4], cl[4];
#pragma unroll
                for (int d = 0; d < 4; ++d) {
                    ch[d] = bf16_of(c2f[d]);
                    cl[d] = bf16_of(c2f[d] - bf16_back(ch[d]));
                }
                float b = -L2E * (c.x * c.x + c.y * c.y + c.z * c.z + c.w * c.w);
                unsigned short bh = bf16_of(b);
                unsigned short bl = bf16_of(b - bf16_back(bh));
                uint4 e;
                if (qq == 0) {
                    e.x = bcat(ch[0], ch[1]); e.y = bcat(ch[2], ch[3]);
                    e.z = e.x;                e.w = e.y;       // d4-7 pair with xl
                } else {
                    e.x = bcat(cl[0], cl[1]); e.y = bcat(cl[2], cl[3]);
                    e.z = bcat(bh, bl);       e.w = 0;         // d12=bh, d13=bl
                }
                tbl[f] = e;
            } else {
                int g = f - 512;                  // 0..511: V'-frags
                int c = g >> 6, qq = (g >> 4) & 3, n = g & 15;
                unsigned rr[4];
#pragma unroll
                for (int r = 0; r < 4; ++r) {
                    int j0 = 2 * r, j1 = 2 * r + 1;
                    int k0 = 32 * c + (j0 < 4 ? 4 * qq + j0 : 16 + 4 * qq + j0 - 4);
                    int k1 = 32 * c + (j1 < 4 ? 4 * qq + j1 : 16 + 4 * qq + j1 - 4);
                    float v0 = (n < 4) ? center[k0 * 4 + n] : (n == 4 ? 1.f : 0.f);
                    float v1 = (n < 4) ? center[k1 * 4 + n] : (n == 4 ? 1.f : 0.f);
                    rr[r] = bcat(bf16_of(v0), bf16_of(v1));
                }
                tbl[f] = make_uint4(rr[0], rr[1], rr[2], rr[3]);
            }
        }
    }
    __syncthreads();

    const int lane = threadIdx.x & 63;
    const int wv   = threadIdx.x >> 6;          // 0..3 waves in block
    const int q    = lane >> 4;
    const int ml   = lane & 15;
    const int l32  = lane & 31;
    const int mbase = blockIdx.x * ((BLK / 64) * 16 * T) + wv * (16 * T);
    const float4* __restrict__ x4 = reinterpret_cast<const float4*>(x);
    const uint4* ta = tbl;                      // compact A-frags [e*32 + lane32]
    const uint4* tv = tbl + 512;                // V'-frags [c*64 + lane]

    union Frag { uint4 u4; unsigned u[4]; short8 v; };

    // ---- Xext B-frags: q0=[xh|xl], q1=[xh|1,1,0], q2/3=0 ----
    Frag B[T];
#pragma unroll
    for (int t = 0; t < T; ++t) {
        float4 xv = x4[mbase + t * 16 + ml];
        float xf[4] = {xv.x, xv.y, xv.z, xv.w};
        unsigned short xh[4], xl[4];
#pragma unroll
        for (int d = 0; d < 4; ++d) {
            xh[d] = bf16_of(xf[d]);
            xl[d] = bf16_of(xf[d] - bf16_back(xh[d]));
        }
        unsigned h01 = bcat(xh[0], xh[1]), h23 = bcat(xh[2], xh[3]);
        unsigned l01 = bcat(xl[0], xl[1]), l23 = bcat(xl[2], xl[3]);
        const unsigned ONE2 = 0x3F803F80u;      // {1.0bf16, 1.0bf16}
        B[t].u[0] = (q <= 1) ? h01 : 0;
        B[t].u[1] = (q <= 1) ? h23 : 0;
        B[t].u[2] = (q == 0) ? l01 : ((q == 1) ? ONE2 : 0);
        B[t].u[3] = (q == 0) ? l23 : 0;
    }

    floatx4 O[T];
#pragma unroll
    for (int t = 0; t < T; ++t) O[t] = (floatx4){0.f, 0.f, 0.f, 0.f};
    const floatx4 Z4 = (floatx4){0.f, 0.f, 0.f, 0.f};

    // ---- software-pipelined chunk loop: prefetch c+1 while computing c ----
    // A-loads are unmasked: q>=2 lanes read the q&1 copy; their B-slots are
    // structurally zero so the MFMA annihilates the garbage.
    Frag a0, a1, vf;
    a0.u4 = ta[0 * 32 + l32];
    a1.u4 = ta[1 * 32 + l32];
    vf.u4 = tv[0 * 64 + lane];

    for (int c = 0; c < 8; ++c) {               // 32 centers per chunk
        Frag na0, na1, nvf;
        int cn = (c + 1) & 7;                   // wraps on last iter (harmless)
        na0.u4 = ta[(2 * cn) * 32 + l32];
        na1.u4 = ta[(2 * cn + 1) * 32 + l32];
        nvf.u4 = tv[cn * 64 + lane];
#pragma unroll
        for (int t = 0; t < T; ++t) {
            floatx4 S0 = __builtin_amdgcn_mfma_f32_16x16x32_bf16(a0.v, B[t].v, Z4, 0, 0, 0);
            floatx4 S1 = __builtin_amdgcn_mfma_f32_16x16x32_bf16(a1.v, B[t].v, Z4, 0, 0, 0);
            Frag p;
            p.u[0] = pack_bf16(fast_exp2(S0[0]), fast_exp2(S0[1]));
            p.u[1] = pack_bf16(fast_exp2(S0[2]), fast_exp2(S0[3]));
            p.u[2] = pack_bf16(fast_exp2(S1[0]), fast_exp2(S1[1]));
            p.u[3] = pack_bf16(fast_exp2(S1[2]), fast_exp2(S1[3]));
            O[t] = __builtin_amdgcn_mfma_f32_16x16x32_bf16(p.v, vf.v, O[t], 0, 0, 0);
        }
        a0 = na0; a1 = na1; vf = nvf;
    }

    // ---- epilogue: D col n = lane&15, row m = q*4 + r; col 4 = denominator.
#pragma unroll
    for (int t = 0; t < T; ++t) {
#pragma unroll
        for (int r = 0; r < 4; ++r) {
            float den = __shfl(O[t][r], (lane & 48) + 4, 64);
            float val = O[t][r] * fast_rcp(den);
            int m = mbase + t * 16 + q * 4 + r;
            if (ml < 4) out[m * 4 + ml] = val;
        }
    }
}

extern "C" void kernel_launch(void* const* d_in, const int* in_sizes, int n_in,
                              void* d_out, int out_size, void* d_ws, size_t ws_size,
                              hipStream_t stream) {
    const float* x      = (const float*)d_in[0];   // [8, 262144] fp32
    const float* center = (const float*)d_in[1];   // [256, 4] fp32
    float* out = (float*)d_out;
    (void)d_ws; (void)ws_size;                     // ws poison is unconditional (R14)

    int nvec   = in_sizes[0] / 4;                  // 524288 m-vectors
    int blocks = nvec / ((BLK / 64) * 16 * T);     // 2048 blocks (4 waves, 256 m)
    vq_main<<<blocks, BLK, 0, stream>>>(x, center, out);
}